// Round 1
// baseline (497.271 us; speedup 1.0000x reference)
//
#include <hip/hip_runtime.h>
#include <math.h>

#define S 1024
#define D 64

__device__ __forceinline__ float waveSum(float v){
  #pragma unroll
  for(int o=32;o>0;o>>=1) v += __shfl_xor(v,o,64);
  return v;
}
__device__ __forceinline__ float waveMin(float v){
  #pragma unroll
  for(int o=32;o>0;o>>=1) v = fminf(v,__shfl_xor(v,o,64));
  return v;
}
// 256-thread block reductions (4 waves). Leading sync guards LDS reuse.
__device__ __forceinline__ float blockSum256(float v, float* red){
  float w = waveSum(v);
  int wid = threadIdx.x>>6;
  __syncthreads();
  if((threadIdx.x&63)==0) red[wid]=w;
  __syncthreads();
  return red[0]+red[1]+red[2]+red[3];
}
__device__ __forceinline__ float blockMin256(float v, float* red){
  float w = waveMin(v);
  int wid = threadIdx.x>>6;
  __syncthreads();
  if((threadIdx.x&63)==0) red[wid]=w;
  __syncthreads();
  return fminf(fminf(red[0],red[1]),fminf(red[2],red[3]));
}

// K1: q/k/v projections, expmap0(q), expmap0(k), squared norms, v_r init
__global__ __launch_bounds__(64) void k_proj(
  const float* __restrict__ qin, const float* __restrict__ kin, const float* __restrict__ vin,
  const float* __restrict__ Wq, const float* __restrict__ bq,
  const float* __restrict__ Wk, const float* __restrict__ bk,
  const float* __restrict__ Wv, const float* __restrict__ bv,
  const float* __restrict__ vrand,
  float* __restrict__ q_hyp, float* __restrict__ k_hyp,
  float* __restrict__ vproj, float* __restrict__ kproj,
  float* __restrict__ q2, float* __restrict__ k2, float* __restrict__ v_r)
{
  const int i = blockIdx.x, d = threadIdx.x;
  __shared__ float lq[D], lk[D], lv[D];
  lq[d]=qin[i*D+d]; lk[d]=kin[i*D+d]; lv[d]=vin[i*D+d];
  __syncthreads();
  float aq=bq[d], ak=bk[d], av=bv[d];
  const float4* wq4=(const float4*)(Wq + d*D);
  const float4* wk4=(const float4*)(Wk + d*D);
  const float4* wv4=(const float4*)(Wv + d*D);
  #pragma unroll
  for(int e=0;e<16;e++){
    float4 a=wq4[e], b=wk4[e], c=wv4[e];
    aq += lq[4*e]*a.x + lq[4*e+1]*a.y + lq[4*e+2]*a.z + lq[4*e+3]*a.w;
    ak += lk[4*e]*b.x + lk[4*e+1]*b.y + lk[4*e+2]*b.z + lk[4*e+3]*b.w;
    av += lv[4*e]*c.x + lv[4*e+1]*c.y + lv[4*e+2]*c.z + lv[4*e+3]*c.w;
  }
  // expmap0(q)
  float nq = sqrtf(waveSum(aq*aq)+1e-15f);
  float qh = tanhf(nq)*aq/nq;
  q_hyp[i*D+d]=qh;
  float q2v = waveSum(qh*qh);
  if(d==0) q2[i]=q2v;
  // expmap0(k)
  float nk = sqrtf(waveSum(ak*ak)+1e-15f);
  float kh = tanhf(nk)*ak/nk;
  k_hyp[i*D+d]=kh;
  float k2v = waveSum(kh*kh);
  if(d==0) k2[i]=k2v;
  vproj[i*D+d]=av;
  kproj[i*D+d]=ak;
  // v_r = normalize(v_rand_init) over D, eps=1e-12
  float vr = vrand[i*D+d];
  float nn = sqrtf(waveSum(vr*vr));
  v_r[i*D+d] = vr/fmaxf(nn,1e-12f);
}

// K2: dist row -> min -> w_un -> w_sum -> entropy/eff_mass. One block per query.
__global__ __launch_bounds__(256) void k_weights(
  const float* __restrict__ q_hyp, const float* __restrict__ k_hyp,
  const float* __restrict__ q2a, const float* __restrict__ k2a,
  float* __restrict__ wbuf, float* __restrict__ wsum, float* __restrict__ effm)
{
  const int i=blockIdx.x, tid=threadIdx.x;
  __shared__ float qv[D];
  __shared__ float red[4];
  if(tid<D) qv[tid]=q_hyp[i*D+tid];
  __syncthreads();
  const float x2=q2a[i];
  const float B=1.f-x2;
  float dist[4];
  float mn=3.4e38f;
  #pragma unroll
  for(int t=0;t<4;t++){
    const int j=tid+t*256;
    const float4* yr=(const float4*)(k_hyp + j*D);
    float dot=0.f;
    #pragma unroll
    for(int e=0;e<16;e++){
      float4 y=yr[e];
      dot += qv[4*e]*y.x + qv[4*e+1]*y.y + qv[4*e+2]*y.z + qv[4*e+3]*y.w;
    }
    const float y2=k2a[j];
    const float A=1.f-2.f*dot+y2;
    const float den=fmaxf(1.f-2.f*dot+x2*y2,1e-15f);
    const float num2=fmaxf(A*A*x2 + B*B*y2 - 2.f*A*B*dot, 0.f);
    const float nn=sqrtf(num2/(den*den)+1e-15f);
    dist[t]=2.f*atanhf(fminf(nn,0.99999994f));
    mn=fminf(mn,dist[t]);
  }
  mn=blockMin256(mn,red);
  float w[4]; float s=0.f;
  #pragma unroll
  for(int t=0;t<4;t++){
    w[t]=expf(mn-dist[t]);
    s+=w[t];
    wbuf[(size_t)i*S + tid + t*256]=w[t];
  }
  s=blockSum256(s,red)+1e-8f;
  if(tid==0) wsum[i]=s;
  const float inv=1.f/s;
  float ent=0.f;
  #pragma unroll
  for(int t=0;t<4;t++){
    const float pp=w[t]*inv;
    ent -= pp*logf(pp+1e-8f);
  }
  ent=blockSum256(ent,red);
  if(tid==0) effm[i]=expf(ent);
}

// K3: h = Wp @ v, centroid = Wp @ k_pre, then expmap0(centroid). 4 rows/block (1 wave each).
__global__ __launch_bounds__(256) void k_hcent(
  const float* __restrict__ wbuf, const float* __restrict__ wsum,
  const float* __restrict__ vproj, const float* __restrict__ kproj,
  float* __restrict__ h, float* __restrict__ c_hyp, float* __restrict__ c2)
{
  const int r=threadIdx.x>>6, d=threadIdx.x&63;
  const int i=blockIdx.x*4+r;
  const float inv=1.f/wsum[i];
  const float* wr = wbuf + (size_t)i*S;
  float ha=0.f, ca=0.f;
  #pragma unroll 8
  for(int j=0;j<S;j++){
    const float w=wr[j]*inv;
    ha += w*vproj[j*D+d];
    ca += w*kproj[j*D+d];
  }
  h[i*D+d]=ha;
  const float n=sqrtf(waveSum(ca*ca)+1e-15f);
  const float ch=tanhf(n)*ca/n;
  c_hyp[i*D+d]=ch;
  const float c2v=waveSum(ch*ch);
  if(d==0) c2[i]=c2v;
}

// K4: second distance pass: alpha/beta coefficients (weighted_k = a*c + b*y),
// variance, tension. One block per query.
__global__ __launch_bounds__(256) void k_ab(
  const float* __restrict__ c_hyp, const float* __restrict__ k_hyp,
  const float* __restrict__ c2a, const float* __restrict__ k2a,
  const float* __restrict__ wbuf, const float* __restrict__ wsum,
  const float* __restrict__ effm, const float* __restrict__ tau_p,
  float* __restrict__ av, float* __restrict__ bv,
  float* __restrict__ varr, float* __restrict__ tens)
{
  const int i=blockIdx.x, tid=threadIdx.x;
  __shared__ float cv[D];
  __shared__ float red[4];
  if(tid<D) cv[tid]=c_hyp[i*D+tid];
  __syncthreads();
  const float x2=c2a[i];
  const float Bc=1.f-x2;
  const float maxB=fmaxf(Bc,1e-15f);
  const float inv=1.f/wsum[i];
  float var=0.f;
  #pragma unroll
  for(int t=0;t<4;t++){
    const int j=tid+t*256;
    const float4* yr=(const float4*)(k_hyp + j*D);
    float dot=0.f;
    #pragma unroll
    for(int e=0;e<16;e++){
      float4 y=yr[e];
      dot += cv[4*e]*y.x + cv[4*e+1]*y.y + cv[4*e+2]*y.z + cv[4*e+3]*y.w;
    }
    const float y2=k2a[j];
    const float A=1.f-2.f*dot+y2;
    const float den=fmaxf(1.f-2.f*dot+x2*y2,1e-15f);
    const float num2=fmaxf(A*A*x2 + Bc*Bc*y2 - 2.f*A*Bc*dot, 0.f);
    const float nn=sqrtf(num2/(den*den)+1e-15f);
    const float art=atanhf(fminf(nn,0.99999994f));
    const float c2k=2.f*art;
    const float w=wbuf[(size_t)i*S+j];
    var += (w*inv)*c2k*c2k;
    const float coef=sqrtf(w+1e-8f)*maxB*art/(nn*den);
    av[(size_t)i*S+j]=-coef*A;
    bv[(size_t)i*S+j]= coef*Bc;
  }
  var=blockSum256(var,red);
  if(tid==0){ varr[i]=var; tens[i]=var - tau_p[0]*effm[i]; }
}

// K5: 3 power iterations fused. weighted_k_ij = a_ij*c + b_ij*y_j (rank-2), so
// M^T M v = c*sum(p*a) + sum(p*b*y_j), p_ij = a_ij*<c,v> + b_ij*<y_j,v>.
__global__ __launch_bounds__(256) void k_power(
  const float* __restrict__ c_hyp, const float* __restrict__ k_hyp,
  const float* __restrict__ av, const float* __restrict__ bv,
  float* __restrict__ v_r)
{
  const int i=blockIdx.x, tid=threadIdx.x;
  __shared__ float cv[D], vv[D];
  __shared__ float prow[S];
  __shared__ float red[4];
  __shared__ float part[4][D];
  __shared__ float cds;
  if(tid<D){ cv[tid]=c_hyp[i*D+tid]; vv[tid]=v_r[i*D+tid]; }
  __syncthreads();
  for(int it=0; it<3; ++it){
    if(tid<D){
      float cd=waveSum(cv[tid]*vv[tid]);
      if(tid==0) cds=cd;
    }
    __syncthreads();
    const float cdot=cds;
    float sal=0.f;
    #pragma unroll
    for(int t=0;t<4;t++){
      const int j=tid+t*256;
      const float4* yr=(const float4*)(k_hyp + j*D);
      float tt=0.f;
      #pragma unroll
      for(int e=0;e<16;e++){
        float4 y=yr[e];
        tt += vv[4*e]*y.x + vv[4*e+1]*y.y + vv[4*e+2]*y.z + vv[4*e+3]*y.w;
      }
      const float aj=av[(size_t)i*S+j], bj=bv[(size_t)i*S+j];
      const float p=aj*cdot + bj*tt;
      prow[j]=p*bj;
      sal += p*aj;
    }
    const float sa=blockSum256(sal,red);   // also makes prow visible
    const int wv=tid>>6, d=tid&63;
    float acc=0.f;
    const int j0=wv*256;
    #pragma unroll 4
    for(int j=j0;j<j0+256;j++) acc += prow[j]*k_hyp[j*D+d];
    part[wv][d]=acc;
    __syncthreads();
    if(tid<D){
      float od=part[0][tid]+part[1][tid]+part[2][tid]+part[3][tid]+sa*cv[tid];
      float nn=sqrtf(waveSum(od*od));
      vv[tid]=od/fmaxf(nn,1e-12f);
    }
    __syncthreads();
  }
  if(tid<D) v_r[i*D+tid]=vv[tid];
}

// K6: per-row epilogue (fallback dir, pitchfork bifurcation, hyperbolic maps) + out GEMV
__global__ __launch_bounds__(64) void k_final(
  const float* __restrict__ h, const float* __restrict__ v_r,
  const float* __restrict__ c_hyp, const float* __restrict__ c2a,
  const float* __restrict__ q_hyp, const float* __restrict__ q2a,
  const float* __restrict__ varr, const float* __restrict__ tens,
  const float* __restrict__ gu, const float* __restrict__ gamma_p,
  const float* __restrict__ ts_p, const float* __restrict__ Wo,
  const float* __restrict__ bo, float* __restrict__ out)
{
  const int i=blockIdx.x, d=threadIdx.x;
  __shared__ float fused[D];
  const float hd=h[i*D+d];
  const float vr=v_r[i*D+d];
  const float cd=c_hyp[i*D+d];
  const float qd=q_hyp[i*D+d];
  const float c2=c2a[i], q2=q2a[i], var=varr[i], tn=tens[i];
  // transp0back
  const float wpg=vr/fmaxf(1.f-c2,1e-15f);
  // logmap0(q_hyp), logmap0(c_hyp) -> fallback
  const float nq=sqrtf(q2+1e-15f);
  const float qt=atanhf(fminf(nq,0.99999994f))*qd/nq;
  const float ncn=sqrtf(c2+1e-15f);
  const float ct=atanhf(fminf(ncn,0.99999994f))*cd/ncn;
  const float df=qt-ct;
  const float nd=sqrtf(waveSum(df*df));
  const float fb=df/fmaxf(nd,1e-8f);
  const float wp=(var>1e-5f)?wpg:fb;
  // h_comp
  const float hn=sqrtf(waveSum(hd*hd)+1e-15f);
  const float hc=asinhf(hn)*hd/(hn+1e-8f);
  const float x=waveSum(hc*wp);
  const float hmag=sqrtf(waveSum(hc*hc)+1e-15f);
  const float amp=(tn>0.f)? hmag*tanhf(tn) : 0.f;
  // gumbel straight-through: eps_g = +1 iff g0>=g1 iff u0>=u1 (monotone)
  const float u0=gu[i*2], u1=gu[i*2+1];
  const float eg=(u0>=u1)?1.f:-1.f;
  const float dc=tanhf(eg*amp - x);
  const float hp=hc+dc*wp;
  const float hpn=sqrtf(waveSum(hp*hp)+1e-15f)+1e-8f;
  const float hpb=hp*(tanhf(hpn*ts_p[0])/hpn);
  // expmap0 then logmap0
  const float n2=sqrtf(waveSum(hpb*hpb)+1e-15f);
  const float hyp=tanhf(n2)*hpb/n2;
  const float n3=sqrtf(waveSum(hyp*hyp)+1e-15f);
  const float bif=atanhf(fminf(n3,0.99999994f))*hyp/n3;
  const float gate=1.f/(1.f+expf(-gamma_p[0]));
  fused[d]=(1.f-gate)*hd + gate*bif;
  __syncthreads();
  float acc=bo[d];
  const float4* wo4=(const float4*)(Wo + d*D);
  #pragma unroll
  for(int e=0;e<16;e++){
    float4 wv=wo4[e];
    acc += fused[4*e]*wv.x + fused[4*e+1]*wv.y + fused[4*e+2]*wv.z + fused[4*e+3]*wv.w;
  }
  out[i*D+d]=acc;
}

extern "C" void kernel_launch(void* const* d_in, const int* in_sizes, int n_in,
                              void* d_out, int out_size, void* d_ws, size_t ws_size,
                              hipStream_t stream)
{
  const float* qin=(const float*)d_in[0];
  const float* kin=(const float*)d_in[1];
  const float* vin=(const float*)d_in[2];
  const float* Wq=(const float*)d_in[3];
  const float* bq=(const float*)d_in[4];
  const float* Wk=(const float*)d_in[5];
  const float* bk=(const float*)d_in[6];
  const float* Wv=(const float*)d_in[7];
  const float* bv=(const float*)d_in[8];
  const float* Wo=(const float*)d_in[9];
  const float* bo=(const float*)d_in[10];
  const float* tau=(const float*)d_in[11];
  const float* gamma=(const float*)d_in[12];
  const float* tscale=(const float*)d_in[13];
  const float* gu=(const float*)d_in[14];
  const float* vrand=(const float*)d_in[15];
  float* out=(float*)d_out;

  float* p=(float*)d_ws;
  float* q_hyp=p; p+=S*D;
  float* k_hyp=p; p+=S*D;
  float* vproj=p; p+=S*D;
  float* kproj=p; p+=S*D;
  float* v_r=p;   p+=S*D;
  float* h=p;     p+=S*D;
  float* c_hyp=p; p+=S*D;
  float* q2=p;   p+=S;
  float* k2=p;   p+=S;
  float* c2=p;   p+=S;
  float* wsum=p; p+=S;
  float* effm=p; p+=S;
  float* varr=p; p+=S;
  float* tens=p; p+=S;
  float* wbuf=p; p+=(size_t)S*S;
  float* av=p;   p+=(size_t)S*S;
  float* bvv=p;  p+=(size_t)S*S;

  k_proj<<<S,64,0,stream>>>(qin,kin,vin,Wq,bq,Wk,bk,Wv,bv,vrand,
                            q_hyp,k_hyp,vproj,kproj,q2,k2,v_r);
  k_weights<<<S,256,0,stream>>>(q_hyp,k_hyp,q2,k2,wbuf,wsum,effm);
  k_hcent<<<S/4,256,0,stream>>>(wbuf,wsum,vproj,kproj,h,c_hyp,c2);
  k_ab<<<S,256,0,stream>>>(c_hyp,k_hyp,c2,k2,wbuf,wsum,effm,tau,av,bvv,varr,tens);
  k_power<<<S,256,0,stream>>>(c_hyp,k_hyp,av,bvv,v_r);
  k_final<<<S,64,0,stream>>>(h,v_r,c_hyp,c2,q_hyp,q2,varr,tens,gu,gamma,tscale,Wo,bo,out);
}

// Round 2
// 248.500 us; speedup vs baseline: 2.0011x; 2.0011x over previous
//
#include <hip/hip_runtime.h>
#include <math.h>

#define S 1024
#define D 64

__device__ __forceinline__ float waveSum(float v){
  #pragma unroll
  for(int o=32;o>0;o>>=1) v += __shfl_xor(v,o,64);
  return v;
}
__device__ __forceinline__ float waveMin(float v){
  #pragma unroll
  for(int o=32;o>0;o>>=1) v = fminf(v,__shfl_xor(v,o,64));
  return v;
}
// 256-thread block reductions (4 waves). Leading sync guards LDS reuse.
__device__ __forceinline__ float blockSum256(float v, float* red){
  float w = waveSum(v);
  int wid = threadIdx.x>>6;
  __syncthreads();
  if((threadIdx.x&63)==0) red[wid]=w;
  __syncthreads();
  return red[0]+red[1]+red[2]+red[3];
}
__device__ __forceinline__ float blockMin256(float v, float* red){
  float w = waveMin(v);
  int wid = threadIdx.x>>6;
  __syncthreads();
  if((threadIdx.x&63)==0) red[wid]=w;
  __syncthreads();
  return fminf(fminf(red[0],red[1]),fminf(red[2],red[3]));
}

// K1: q/k/v projections, expmap0(q), expmap0(k), squared norms, v_r init
__global__ __launch_bounds__(64) void k_proj(
  const float* __restrict__ qin, const float* __restrict__ kin, const float* __restrict__ vin,
  const float* __restrict__ Wq, const float* __restrict__ bq,
  const float* __restrict__ Wk, const float* __restrict__ bk,
  const float* __restrict__ Wv, const float* __restrict__ bv,
  const float* __restrict__ vrand,
  float* __restrict__ q_hyp, float* __restrict__ k_hyp,
  float* __restrict__ vproj, float* __restrict__ kproj,
  float* __restrict__ q2, float* __restrict__ k2, float* __restrict__ v_r)
{
  const int i = blockIdx.x, d = threadIdx.x;
  __shared__ float lq[D], lk[D], lv[D];
  lq[d]=qin[i*D+d]; lk[d]=kin[i*D+d]; lv[d]=vin[i*D+d];
  __syncthreads();
  float aq=bq[d], ak=bk[d], av=bv[d];
  const float4* wq4=(const float4*)(Wq + d*D);
  const float4* wk4=(const float4*)(Wk + d*D);
  const float4* wv4=(const float4*)(Wv + d*D);
  #pragma unroll
  for(int e=0;e<16;e++){
    float4 a=wq4[e], b=wk4[e], c=wv4[e];
    aq += lq[4*e]*a.x + lq[4*e+1]*a.y + lq[4*e+2]*a.z + lq[4*e+3]*a.w;
    ak += lk[4*e]*b.x + lk[4*e+1]*b.y + lk[4*e+2]*b.z + lk[4*e+3]*b.w;
    av += lv[4*e]*c.x + lv[4*e+1]*c.y + lv[4*e+2]*c.z + lv[4*e+3]*c.w;
  }
  // expmap0(q)
  float nq = sqrtf(waveSum(aq*aq)+1e-15f);
  float qh = tanhf(nq)*aq/nq;
  q_hyp[i*D+d]=qh;
  float q2v = waveSum(qh*qh);
  if(d==0) q2[i]=q2v;
  // expmap0(k)
  float nk = sqrtf(waveSum(ak*ak)+1e-15f);
  float kh = tanhf(nk)*ak/nk;
  k_hyp[i*D+d]=kh;
  float k2v = waveSum(kh*kh);
  if(d==0) k2[i]=k2v;
  vproj[i*D+d]=av;
  kproj[i*D+d]=ak;
  // v_r = normalize(v_rand_init) over D, eps=1e-12
  float vr = vrand[i*D+d];
  float nn = sqrtf(waveSum(vr*vr));
  v_r[i*D+d] = vr/fmaxf(nn,1e-12f);
}

// K2: dist row -> min -> w_un -> w_sum -> entropy/eff_mass. One block per query.
__global__ __launch_bounds__(256) void k_weights(
  const float* __restrict__ q_hyp, const float* __restrict__ k_hyp,
  const float* __restrict__ q2a, const float* __restrict__ k2a,
  float* __restrict__ wbuf, float* __restrict__ wsum, float* __restrict__ effm)
{
  const int i=blockIdx.x, tid=threadIdx.x;
  __shared__ float qv[D];
  __shared__ float red[4];
  if(tid<D) qv[tid]=q_hyp[i*D+tid];
  __syncthreads();
  const float x2=q2a[i];
  const float B=1.f-x2;
  float dist[4];
  float mn=3.4e38f;
  #pragma unroll
  for(int t=0;t<4;t++){
    const int j=tid+t*256;
    const float4* yr=(const float4*)(k_hyp + j*D);
    float dot=0.f;
    #pragma unroll
    for(int e=0;e<16;e++){
      float4 y=yr[e];
      dot += qv[4*e]*y.x + qv[4*e+1]*y.y + qv[4*e+2]*y.z + qv[4*e+3]*y.w;
    }
    const float y2=k2a[j];
    const float A=1.f-2.f*dot+y2;
    const float den=fmaxf(1.f-2.f*dot+x2*y2,1e-15f);
    const float num2=fmaxf(A*A*x2 + B*B*y2 - 2.f*A*B*dot, 0.f);
    const float nn=sqrtf(num2/(den*den)+1e-15f);
    dist[t]=2.f*atanhf(fminf(nn,0.99999994f));
    mn=fminf(mn,dist[t]);
  }
  mn=blockMin256(mn,red);
  float w[4]; float s=0.f;
  #pragma unroll
  for(int t=0;t<4;t++){
    w[t]=expf(mn-dist[t]);
    s+=w[t];
    wbuf[(size_t)i*S + tid + t*256]=w[t];
  }
  s=blockSum256(s,red)+1e-8f;
  if(tid==0) wsum[i]=s;
  const float inv=1.f/s;
  float ent=0.f;
  #pragma unroll
  for(int t=0;t<4;t++){
    const float pp=w[t]*inv;
    ent -= pp*logf(pp+1e-8f);
  }
  ent=blockSum256(ent,red);
  if(tid==0) effm[i]=expf(ent);
}

// K3: h = Wp @ v, centroid = Wp @ k_pre, then expmap0(centroid). 4 rows/block (1 wave each).
__global__ __launch_bounds__(256) void k_hcent(
  const float* __restrict__ wbuf, const float* __restrict__ wsum,
  const float* __restrict__ vproj, const float* __restrict__ kproj,
  float* __restrict__ h, float* __restrict__ c_hyp, float* __restrict__ c2)
{
  const int r=threadIdx.x>>6, d=threadIdx.x&63;
  const int i=blockIdx.x*4+r;
  const float inv=1.f/wsum[i];
  const float* wr = wbuf + (size_t)i*S;
  float ha=0.f, ca=0.f;
  #pragma unroll 8
  for(int j=0;j<S;j++){
    const float w=wr[j]*inv;
    ha += w*vproj[j*D+d];
    ca += w*kproj[j*D+d];
  }
  h[i*D+d]=ha;
  const float n=sqrtf(waveSum(ca*ca)+1e-15f);
  const float ch=tanhf(n)*ca/n;
  c_hyp[i*D+d]=ch;
  const float c2v=waveSum(ch*ch);
  if(d==0) c2[i]=c2v;
}

// K4: second distance pass: alpha/beta coefficients (weighted_k = a*c + b*y),
// variance, tension. One block per query. a,b packed as float2.
__global__ __launch_bounds__(256) void k_ab(
  const float* __restrict__ c_hyp, const float* __restrict__ k_hyp,
  const float* __restrict__ c2a, const float* __restrict__ k2a,
  const float* __restrict__ wbuf, const float* __restrict__ wsum,
  const float* __restrict__ effm, const float* __restrict__ tau_p,
  float2* __restrict__ ab,
  float* __restrict__ varr, float* __restrict__ tens)
{
  const int i=blockIdx.x, tid=threadIdx.x;
  __shared__ float cv[D];
  __shared__ float red[4];
  if(tid<D) cv[tid]=c_hyp[i*D+tid];
  __syncthreads();
  const float x2=c2a[i];
  const float Bc=1.f-x2;
  const float maxB=fmaxf(Bc,1e-15f);
  const float inv=1.f/wsum[i];
  float var=0.f;
  #pragma unroll
  for(int t=0;t<4;t++){
    const int j=tid+t*256;
    const float4* yr=(const float4*)(k_hyp + j*D);
    float dot=0.f;
    #pragma unroll
    for(int e=0;e<16;e++){
      float4 y=yr[e];
      dot += cv[4*e]*y.x + cv[4*e+1]*y.y + cv[4*e+2]*y.z + cv[4*e+3]*y.w;
    }
    const float y2=k2a[j];
    const float A=1.f-2.f*dot+y2;
    const float den=fmaxf(1.f-2.f*dot+x2*y2,1e-15f);
    const float num2=fmaxf(A*A*x2 + Bc*Bc*y2 - 2.f*A*Bc*dot, 0.f);
    const float nn=sqrtf(num2/(den*den)+1e-15f);
    const float art=atanhf(fminf(nn,0.99999994f));
    const float c2k=2.f*art;
    const float w=wbuf[(size_t)i*S+j];
    var += (w*inv)*c2k*c2k;
    const float coef=sqrtf(w+1e-8f)*maxB*art/(nn*den);
    float2 t2; t2.x=-coef*A; t2.y=coef*Bc;
    ab[(size_t)i*S+j]=t2;
  }
  var=blockSum256(var,red);
  if(tid==0){ varr[i]=var; tens[i]=var - tau_p[0]*effm[i]; }
}

// K5: 3 power iterations fused. weighted_k_ij = a_ij*c + b_ij*y_j (rank-2), so
// M^T M v = c*sum(p*a) + sum(p*b*y_j), p_ij = a_ij*<c,v> + b_ij*<y_j,v>.
// v2: launch_bounds(256,4) for 16 waves/CU; pass2 uses float4 loads with
// (d-quad, j-group) thread mapping + LDS partial reduce.
__global__ __launch_bounds__(256,4) void k_power(
  const float* __restrict__ c_hyp, const float* __restrict__ k_hyp,
  const float2* __restrict__ ab,
  float* __restrict__ v_r)
{
  const int i=blockIdx.x, tid=threadIdx.x;
  __shared__ float cv[D], vv[D];
  __shared__ float prow[S];
  __shared__ float red[4];
  __shared__ float part[16*D];   // part[g][d]
  __shared__ float cds;
  if(tid<D){ cv[tid]=c_hyp[i*D+tid]; vv[tid]=v_r[i*D+tid]; }
  __syncthreads();
  const float4* cv4=(const float4*)cv;
  const float4* vv4=(const float4*)vv;
  const int dq=tid&15, g=tid>>4;
  for(int it=0; it<3; ++it){
    if(tid<D){
      float cd=waveSum(cv[tid]*vv[tid]);
      if(tid==0) cds=cd;
    }
    __syncthreads();
    const float cdot=cds;
    // pass 1: prow[j] = p_ij*b_ij, sal += p_ij*a_ij
    float sal=0.f;
    #pragma unroll 1
    for(int t=0;t<4;t++){
      const int j=tid+t*256;
      const float4* yr=(const float4*)(k_hyp + j*D);
      float tt=0.f;
      #pragma unroll 4
      for(int e=0;e<16;e++){
        float4 y=yr[e];
        float4 q=vv4[e];
        tt += q.x*y.x + q.y*y.y + q.z*y.z + q.w*y.w;
      }
      const float2 abj=ab[(size_t)i*S+j];
      const float p=abj.x*cdot + abj.y*tt;
      prow[j]=p*abj.y;
      sal += p*abj.x;
    }
    const float sa=blockSum256(sal,red);   // barriers also publish prow
    // pass 2: out[d] = sum_j prow[j]*k_hyp[j][d] ; thread = (dq, g), 64 j each
    float4 acc; acc.x=0.f; acc.y=0.f; acc.z=0.f; acc.w=0.f;
    #pragma unroll 4
    for(int jj=0;jj<64;jj++){
      const int j=jj*16+g;
      const float4 y=((const float4*)(k_hyp + j*D))[dq];
      const float pb=prow[j];
      acc.x += pb*y.x; acc.y += pb*y.y; acc.z += pb*y.z; acc.w += pb*y.w;
    }
    ((float4*)part)[tid]=acc;  // part[g][4*dq..4*dq+3]
    __syncthreads();
    if(tid<D){
      float od=sa*cv[tid];
      #pragma unroll
      for(int gg=0;gg<16;gg++) od += part[gg*D+tid];
      float nn=sqrtf(waveSum(od*od));
      vv[tid]=od/fmaxf(nn,1e-12f);
    }
    __syncthreads();
  }
  if(tid<D) v_r[i*D+tid]=vv[tid];
}

// K6: per-row epilogue (fallback dir, pitchfork bifurcation, hyperbolic maps) + out GEMV
__global__ __launch_bounds__(64) void k_final(
  const float* __restrict__ h, const float* __restrict__ v_r,
  const float* __restrict__ c_hyp, const float* __restrict__ c2a,
  const float* __restrict__ q_hyp, const float* __restrict__ q2a,
  const float* __restrict__ varr, const float* __restrict__ tens,
  const float* __restrict__ gu, const float* __restrict__ gamma_p,
  const float* __restrict__ ts_p, const float* __restrict__ Wo,
  const float* __restrict__ bo, float* __restrict__ out)
{
  const int i=blockIdx.x, d=threadIdx.x;
  __shared__ float fused[D];
  const float hd=h[i*D+d];
  const float vr=v_r[i*D+d];
  const float cd=c_hyp[i*D+d];
  const float qd=q_hyp[i*D+d];
  const float c2=c2a[i], q2=q2a[i], var=varr[i], tn=tens[i];
  // transp0back
  const float wpg=vr/fmaxf(1.f-c2,1e-15f);
  // logmap0(q_hyp), logmap0(c_hyp) -> fallback
  const float nq=sqrtf(q2+1e-15f);
  const float qt=atanhf(fminf(nq,0.99999994f))*qd/nq;
  const float ncn=sqrtf(c2+1e-15f);
  const float ct=atanhf(fminf(ncn,0.99999994f))*cd/ncn;
  const float df=qt-ct;
  const float nd=sqrtf(waveSum(df*df));
  const float fb=df/fmaxf(nd,1e-8f);
  const float wp=(var>1e-5f)?wpg:fb;
  // h_comp
  const float hn=sqrtf(waveSum(hd*hd)+1e-15f);
  const float hc=asinhf(hn)*hd/(hn+1e-8f);
  const float x=waveSum(hc*wp);
  const float hmag=sqrtf(waveSum(hc*hc)+1e-15f);
  const float amp=(tn>0.f)? hmag*tanhf(tn) : 0.f;
  // gumbel straight-through: eps_g = +1 iff g0>=g1 iff u0>=u1 (monotone)
  const float u0=gu[i*2], u1=gu[i*2+1];
  const float eg=(u0>=u1)?1.f:-1.f;
  const float dc=tanhf(eg*amp - x);
  const float hp=hc+dc*wp;
  const float hpn=sqrtf(waveSum(hp*hp)+1e-15f)+1e-8f;
  const float hpb=hp*(tanhf(hpn*ts_p[0])/hpn);
  // expmap0 then logmap0
  const float n2=sqrtf(waveSum(hpb*hpb)+1e-15f);
  const float hyp=tanhf(n2)*hpb/n2;
  const float n3=sqrtf(waveSum(hyp*hyp)+1e-15f);
  const float bif=atanhf(fminf(n3,0.99999994f))*hyp/n3;
  const float gate=1.f/(1.f+expf(-gamma_p[0]));
  fused[d]=(1.f-gate)*hd + gate*bif;
  __syncthreads();
  float acc=bo[d];
  const float4* wo4=(const float4*)(Wo + d*D);
  #pragma unroll
  for(int e=0;e<16;e++){
    float4 wv=wo4[e];
    acc += fused[4*e]*wv.x + fused[4*e+1]*wv.y + fused[4*e+2]*wv.z + fused[4*e+3]*wv.w;
  }
  out[i*D+d]=acc;
}

extern "C" void kernel_launch(void* const* d_in, const int* in_sizes, int n_in,
                              void* d_out, int out_size, void* d_ws, size_t ws_size,
                              hipStream_t stream)
{
  const float* qin=(const float*)d_in[0];
  const float* kin=(const float*)d_in[1];
  const float* vin=(const float*)d_in[2];
  const float* Wq=(const float*)d_in[3];
  const float* bq=(const float*)d_in[4];
  const float* Wk=(const float*)d_in[5];
  const float* bk=(const float*)d_in[6];
  const float* Wv=(const float*)d_in[7];
  const float* bv=(const float*)d_in[8];
  const float* Wo=(const float*)d_in[9];
  const float* bo=(const float*)d_in[10];
  const float* tau=(const float*)d_in[11];
  const float* gamma=(const float*)d_in[12];
  const float* tscale=(const float*)d_in[13];
  const float* gu=(const float*)d_in[14];
  const float* vrand=(const float*)d_in[15];
  float* out=(float*)d_out;

  float* p=(float*)d_ws;
  float* q_hyp=p; p+=S*D;
  float* k_hyp=p; p+=S*D;
  float* vproj=p; p+=S*D;
  float* kproj=p; p+=S*D;
  float* v_r=p;   p+=S*D;
  float* h=p;     p+=S*D;
  float* c_hyp=p; p+=S*D;
  float* q2=p;   p+=S;
  float* k2=p;   p+=S;
  float* c2=p;   p+=S;
  float* wsum=p; p+=S;
  float* effm=p; p+=S;
  float* varr=p; p+=S;
  float* tens=p; p+=S;
  float* wbuf=p; p+=(size_t)S*S;
  float2* ab=(float2*)p; p+=(size_t)2*S*S;

  k_proj<<<S,64,0,stream>>>(qin,kin,vin,Wq,bq,Wk,bk,Wv,bv,vrand,
                            q_hyp,k_hyp,vproj,kproj,q2,k2,v_r);
  k_weights<<<S,256,0,stream>>>(q_hyp,k_hyp,q2,k2,wbuf,wsum,effm);
  k_hcent<<<S/4,256,0,stream>>>(wbuf,wsum,vproj,kproj,h,c_hyp,c2);
  k_ab<<<S,256,0,stream>>>(c_hyp,k_hyp,c2,k2,wbuf,wsum,effm,tau,ab,varr,tens);
  k_power<<<S,256,0,stream>>>(c_hyp,k_hyp,ab,v_r);
  k_final<<<S,64,0,stream>>>(h,v_r,c_hyp,c2,q_hyp,q2,varr,tens,gu,gamma,tscale,Wo,bo,out);
}